// Round 3
// baseline (464.411 us; speedup 1.0000x reference)
//
#include <hip/hip_runtime.h>
#include <cmath>

// Problem geometry (fixed by the reference): 128 images of 512x512 f32.
static constexpr int IMH = 512;
static constexpr int IMW = 512;
static constexpr int IMG_PIX = IMH * IMW;

// Tile config for the fused blur kernel
static constexpr int TH = 64;           // output tile height
static constexpr int TW = 64;           // output tile width
static constexpr int GR = TH + 12;      // grad rows needed (76)
static constexpr int GC = TW + 6;       // grad cols needed (70)
static constexpr int GCP = 72;          // padded LDS stride for grad

struct Weights {
    float kx[7];
    float ky[13];
};

__global__ void init_minmax_kernel(int* __restrict__ mm, int nimg) {
    int i = blockIdx.x * blockDim.x + threadIdx.x;
    if (i < nimg) {
        mm[2 * i]     = 0x7f7fffff;  // +FLT_MAX bits (min accumulator)
        mm[2 * i + 1] = 0;           // 0.0f bits (max accumulator; blur > 0)
    }
}

// Fused: Sobel-magnitude grad -> 1x7 blur (reflect, width) -> 13x1 blur
// (reflect, height) -> store blur f32 + per-image min/max reduction.
__global__ __launch_bounds__(256) void blur_kernel(
        const float* __restrict__ in, float* __restrict__ blur,
        int* __restrict__ mm, Weights wt) {
    __shared__ float s_grad[GR][GCP];
    __shared__ float s_bx[GR][TW];
    __shared__ float s_red[16];

    const int img = blockIdx.z;
    const int X0 = blockIdx.x * TW;
    const int Y0 = blockIdx.y * TH;
    const int tid = threadIdx.x;
    const float* __restrict__ ip = in + (size_t)img * IMG_PIX;

    // ---- stage 1: grad on [Y0-6, Y0+TH+6) x [X0-3, X0+TW+3) (valid part) ----
    for (int idx = tid; idx < GR * GC; idx += 256) {
        int lr = idx / GC;
        int lc = idx - lr * GC;
        int gy = Y0 - 6 + lr;
        int gx = X0 - 3 + lc;
        if (gy >= 0 && gy < IMH && gx >= 0 && gx < IMW) {
            // zero-padded central differences (cross-correlation Sobel-style)
            float up = (gy > 0)       ? ip[(gy - 1) * IMW + gx] : 0.0f;
            float dn = (gy < IMH - 1) ? ip[(gy + 1) * IMW + gx] : 0.0f;
            float lf = (gx > 0)       ? ip[gy * IMW + gx - 1] : 0.0f;
            float rt = (gx < IMW - 1) ? ip[gy * IMW + gx + 1] : 0.0f;
            float gv = dn - up;
            float gh = rt - lf;
            float a = gv * gv;
            float b = gh * gh;
            // block fma-contraction so order matches a plain f32 reference
            asm volatile("" : "+v"(a), "+v"(b));
            float s = a + b;
            asm volatile("" : "+v"(s));
            s = s + 1e-6f;
            s_grad[lr][lc] = sqrtf(s);
        }
    }
    __syncthreads();

    // ---- stage 2: horizontal 7-tap blur with reflect cols ----
    for (int idx = tid; idx < GR * TW; idx += 256) {
        int lr = idx >> 6;
        int lc = idx & (TW - 1);
        float acc = 0.0f;
        #pragma unroll
        for (int i = 0; i < 7; ++i) {
            int gc = X0 + lc + i - 3;
            int rc = (gc < 0) ? -gc : ((gc > IMW - 1) ? 2 * (IMW - 1) - gc : gc);
            float p = wt.kx[i] * s_grad[lr][rc - X0 + 3];
            asm volatile("" : "+v"(p));   // keep plain mul + add (no fma chain)
            acc += p;
        }
        s_bx[lr][lc] = acc;
    }
    __syncthreads();

    // ---- stage 3: vertical 13-tap blur with reflect rows + minmax ----
    float tmn = 3.402823466e38f;
    float tmx = 0.0f;
    float* __restrict__ bp = blur + (size_t)img * IMG_PIX;
    for (int idx = tid; idx < TH * TW; idx += 256) {
        int ly = idx >> 6;
        int lx = idx & 63;
        float acc = 0.0f;
        #pragma unroll
        for (int j = 0; j < 13; ++j) {
            int gr = Y0 + ly + j - 6;
            int rr = (gr < 0) ? -gr : ((gr > IMH - 1) ? 2 * (IMH - 1) - gr : gr);
            float p = wt.ky[j] * s_bx[rr - Y0 + 6][lx];
            asm volatile("" : "+v"(p));
            acc += p;
        }
        bp[(Y0 + ly) * IMW + X0 + lx] = acc;
        tmn = fminf(tmn, acc);
        tmx = fmaxf(tmx, acc);
    }

    // wave (64-lane) butterfly reduce, then across the 4 waves, then atomics
    #pragma unroll
    for (int off = 32; off > 0; off >>= 1) {
        tmn = fminf(tmn, __shfl_xor(tmn, off));
        tmx = fmaxf(tmx, __shfl_xor(tmx, off));
    }
    int wid = tid >> 6;
    if ((tid & 63) == 0) {
        s_red[wid] = tmn;
        s_red[8 + wid] = tmx;
    }
    __syncthreads();
    if (tid == 0) {
        float mn = s_red[0], mx = s_red[8];
        #pragma unroll
        for (int w = 1; w < 4; ++w) {
            mn = fminf(mn, s_red[w]);
            mx = fmaxf(mx, s_red[8 + w]);
        }
        // blur values are strictly positive -> float order == int order
        atomicMin(&mm[2 * img], __float_as_int(mn));
        atomicMax(&mm[2 * img + 1], __float_as_int(mx));
    }
}

// Normalize + emit both masks as INT32 0/1 (bool output dtype -> int32).
// blurNe holds blur f32 bit patterns on entry (second half of d_out used as
// scratch); each thread overwrites exactly the elements it read.
__global__ __launch_bounds__(256) void mask_kernel(
        const int* __restrict__ mm, int* __restrict__ edge,
        int* __restrict__ blurNe, long long n4) {
    const long long stride = (long long)gridDim.x * blockDim.x;
    for (long long i = (long long)blockIdx.x * blockDim.x + threadIdx.x;
         i < n4; i += stride) {
        int img = (int)(i >> 16);  // 262144/4 = 65536 vec4 per image
        float mn = __int_as_float(mm[2 * img]);
        float mx = __int_as_float(mm[2 * img + 1]);
        float d = mx - mn;
        int4 vi = reinterpret_cast<const int4*>(blurNe)[i];
        float4 v = make_float4(__int_as_float(vi.x), __int_as_float(vi.y),
                               __int_as_float(vi.z), __int_as_float(vi.w));
        // true division to match reference normalization exactly
        float n0 = (v.x - mn) / d;
        float n1 = (v.y - mn) / d;
        float n2 = (v.z - mn) / d;
        float n3 = (v.w - mn) / d;
        int4 e, ne;
        e.x = (n0 < 0.1f) ? 1 : 0;  ne.x = 1 - e.x;
        e.y = (n1 < 0.1f) ? 1 : 0;  ne.y = 1 - e.y;
        e.z = (n2 < 0.1f) ? 1 : 0;  ne.z = 1 - e.z;
        e.w = (n3 < 0.1f) ? 1 : 0;  ne.w = 1 - e.w;
        reinterpret_cast<int4*>(edge)[i] = e;
        reinterpret_cast<int4*>(blurNe)[i] = ne;
    }
}

extern "C" void kernel_launch(void* const* d_in, const int* in_sizes, int n_in,
                              void* d_out, int out_size, void* d_ws, size_t ws_size,
                              hipStream_t stream) {
    const float* x = (const float*)d_in[0];
    int* out = (int*)d_out;
    const long long N = (long long)in_sizes[0];        // 33554432
    const int nimg = (int)(N / IMG_PIX);               // 128
    float* blur = (float*)(out + N);                   // scratch in 2nd output half
    int* mm = (int*)d_ws;                              // 2 ints per image

    // f32 Gaussian weights, mimicking the jnp float32 ops
    Weights wt;
    {
        float tmp[13];
        float s = 0.0f;
        for (int i = 0; i < 7; ++i) {
            float t = (float)i - 3.0f;
            float u = t / 10.0f;
            tmp[i] = expf(-0.5f * (u * u));
            s += tmp[i];
        }
        for (int i = 0; i < 7; ++i) wt.kx[i] = tmp[i] / s;
        s = 0.0f;
        for (int i = 0; i < 13; ++i) {
            float t = (float)i - 6.0f;
            float u = t / 10.0f;
            tmp[i] = expf(-0.5f * (u * u));
            s += tmp[i];
        }
        for (int i = 0; i < 13; ++i) wt.ky[i] = tmp[i] / s;
    }

    init_minmax_kernel<<<1, 256, 0, stream>>>(mm, nimg);
    blur_kernel<<<dim3(IMW / TW, IMH / TH, nimg), 256, 0, stream>>>(x, blur, mm, wt);
    mask_kernel<<<2048, 256, 0, stream>>>(mm, out, (int*)blur, N / 4);
}

// Round 4
// 270.411 us; speedup vs baseline: 1.7174x; 1.7174x over previous
//
#include <hip/hip_runtime.h>
#include <cmath>

// Problem geometry (fixed by the reference): 128 images of 512x512 f32.
static constexpr int IMH = 512;
static constexpr int IMW = 512;
static constexpr int IMG_PIX = IMH * IMW;

// Tile config
static constexpr int TH = 64;            // output tile height
static constexpr int TW = 64;            // output tile width
static constexpr int INR = 78;           // s_in rows  [Y0-7 .. Y0+70]
static constexpr int INC = 76;           // s_in cols  [X0-4 .. X0+71]
static constexpr int INC4 = 19;          // float4 per s_in row
static constexpr int GR = 76;            // grad rows  [Y0-6 .. Y0+69] (reflected)
static constexpr int GC = 70;            // grad cols  [X0-3 .. X0+66] (reflected)
static constexpr int GCP = 72;           // padded LDS stride for s_grad

struct Weights {
    float kx[7];
    float ky[13];
};

__global__ void init_minmax_kernel(int* __restrict__ mm, int nimg) {
    int i = blockIdx.x * blockDim.x + threadIdx.x;
    if (i < nimg) {
        mm[2 * i]     = 0x7f7fffff;  // +FLT_MAX bits (min accumulator)
        mm[2 * i + 1] = 0;           // 0.0f bits (max accumulator; blur > 0)
    }
}

// Fused: input tile -> Sobel-magnitude grad AT REFLECTED COORDS -> 1x7 blur
// (register window) -> 13x1 blur (register window) -> blur store + minmax.
__global__ __launch_bounds__(256) void blur_kernel(
        const float* __restrict__ in, float* __restrict__ blur,
        int* __restrict__ mm, Weights wt) {
    __shared__ float s_grad[GR * GCP];            // 21888 B
    __shared__ float s_a[INR * INC];              // 23712 B (s_in, then s_bx)
    __shared__ float s_red[16];
    float* s_in = s_a;                            // [INR][INC]
    float* s_bx = s_a;                            // [GR][TW] (19456 B, fits)

    const int img = blockIdx.z;
    const int X0 = blockIdx.x * TW;
    const int Y0 = blockIdx.y * TH;
    const int tid = threadIdx.x;
    const int by0 = Y0 - 7;                       // virtual tile origin
    const int bx0 = X0 - 4;
    const float* __restrict__ ip = in + (size_t)img * IMG_PIX;

    // ---- stage 0: coalesced float4 load of input tile (clamped) ----
    for (int idx = tid; idx < INR * INC4; idx += 256) {
        int r = idx / INC4;
        int q = idx - r * INC4;
        int gy = by0 + r;
        gy = gy < 0 ? 0 : (gy > IMH - 1 ? IMH - 1 : gy);
        int gx = bx0 + q * 4;
        float4 v;
        if (gx >= 0 && gx <= IMW - 4) {
            v = *reinterpret_cast<const float4*>(ip + (size_t)gy * IMW + gx);
        } else {
            int g0 = min(max(gx, 0), IMW - 1);
            int g1 = min(max(gx + 1, 0), IMW - 1);
            int g2 = min(max(gx + 2, 0), IMW - 1);
            int g3 = min(max(gx + 3, 0), IMW - 1);
            const float* rp = ip + (size_t)gy * IMW;
            v = make_float4(rp[g0], rp[g1], rp[g2], rp[g3]);
        }
        *reinterpret_cast<float4*>(&s_in[r * INC + q * 4]) = v;
    }
    __syncthreads();

    // ---- stage 1: grad at reflected coords (reflection hoisted here) ----
    for (int idx = tid; idx < GR * GC; idx += 256) {
        int lr = idx / GC;
        int lc = idx - lr * GC;
        int gy = Y0 - 6 + lr;
        gy = gy < 0 ? -gy : (gy > IMH - 1 ? 2 * (IMH - 1) - gy : gy);
        int gx = X0 - 3 + lc;
        gx = gx < 0 ? -gx : (gx > IMW - 1 ? 2 * (IMW - 1) - gx : gx);
        int a = (gy - by0) * INC + (gx - bx0);
        float up = (gy > 0)       ? s_in[a - INC] : 0.0f;
        float dn = (gy < IMH - 1) ? s_in[a + INC] : 0.0f;
        float lf = (gx > 0)       ? s_in[a - 1]   : 0.0f;
        float rt = (gx < IMW - 1) ? s_in[a + 1]   : 0.0f;
        float gv = dn - up;
        float gh = rt - lf;
        float sa = gv * gv;
        float sb = gh * gh;
        asm volatile("" : "+v"(sa), "+v"(sb));  // block fma contraction
        float s = sa + sb;
        asm volatile("" : "+v"(s));
        s = s + 1e-6f;
        s_grad[lr * GCP + lc] = sqrtf(s);
    }
    __syncthreads();

    // ---- stage 2: horizontal 7-tap blur, 16-wide register window ----
    {
        int row = tid >> 2;             // 0..63
        int c0 = (tid & 3) * 16;        // 0,16,32,48
        #pragma unroll
        for (int pass = 0; pass < 2; ++pass) {
            int r = row + pass * 64;
            if (r < GR) {
                float g[22];
                #pragma unroll
                for (int k = 0; k < 22; ++k) g[k] = s_grad[r * GCP + c0 + k];
                #pragma unroll
                for (int k = 0; k < 16; ++k) {
                    float acc = 0.0f;
                    #pragma unroll
                    for (int i = 0; i < 7; ++i) {
                        float p = wt.kx[i] * g[k + i];
                        asm volatile("" : "+v"(p));  // plain mul + add
                        acc += p;
                    }
                    s_bx[r * TW + c0 + k] = acc;
                }
            }
        }
    }
    __syncthreads();

    // ---- stage 3: vertical 13-tap blur, 16-tall register window + minmax ----
    float tmn = 3.402823466e38f;
    float tmx = 0.0f;
    {
        int c = tid & 63;
        int r0 = (tid >> 6) * 16;       // 0,16,32,48
        float w[28];
        #pragma unroll
        for (int t = 0; t < 28; ++t) w[t] = s_bx[(r0 + t) * TW + c];
        float* __restrict__ bp = blur + (size_t)img * IMG_PIX;
        #pragma unroll
        for (int k = 0; k < 16; ++k) {
            float acc = 0.0f;
            #pragma unroll
            for (int j = 0; j < 13; ++j) {
                float p = wt.ky[j] * w[k + j];
                asm volatile("" : "+v"(p));
                acc += p;
            }
            bp[(size_t)(Y0 + r0 + k) * IMW + X0 + c] = acc;
            tmn = fminf(tmn, acc);
            tmx = fmaxf(tmx, acc);
        }
    }

    // wave (64-lane) butterfly reduce, then across the 4 waves, then atomics
    #pragma unroll
    for (int off = 32; off > 0; off >>= 1) {
        tmn = fminf(tmn, __shfl_xor(tmn, off));
        tmx = fmaxf(tmx, __shfl_xor(tmx, off));
    }
    int wid = tid >> 6;
    if ((tid & 63) == 0) {
        s_red[wid] = tmn;
        s_red[8 + wid] = tmx;
    }
    __syncthreads();
    if (tid == 0) {
        float mn = s_red[0], mx = s_red[8];
        #pragma unroll
        for (int w2 = 1; w2 < 4; ++w2) {
            mn = fminf(mn, s_red[w2]);
            mx = fmaxf(mx, s_red[8 + w2]);
        }
        // blur values are strictly positive -> float order == int order
        atomicMin(&mm[2 * img], __float_as_int(mn));
        atomicMax(&mm[2 * img + 1], __float_as_int(mx));
    }
}

// Normalize + emit both masks as INT32 0/1 (bool output dtype -> int32).
// blurNe holds blur f32 bit patterns on entry (second half of d_out used as
// scratch); each thread overwrites exactly the elements it read.
__global__ __launch_bounds__(256) void mask_kernel(
        const int* __restrict__ mm, int* __restrict__ edge,
        int* __restrict__ blurNe, long long n4) {
    const long long stride = (long long)gridDim.x * blockDim.x;
    for (long long i = (long long)blockIdx.x * blockDim.x + threadIdx.x;
         i < n4; i += stride) {
        int img = (int)(i >> 16);  // 262144/4 = 65536 vec4 per image
        float mn = __int_as_float(mm[2 * img]);
        float mx = __int_as_float(mm[2 * img + 1]);
        float d = mx - mn;
        int4 vi = reinterpret_cast<const int4*>(blurNe)[i];
        float4 v = make_float4(__int_as_float(vi.x), __int_as_float(vi.y),
                               __int_as_float(vi.z), __int_as_float(vi.w));
        // true division to match reference normalization exactly
        float n0 = (v.x - mn) / d;
        float n1 = (v.y - mn) / d;
        float n2 = (v.z - mn) / d;
        float n3 = (v.w - mn) / d;
        int4 e, ne;
        e.x = (n0 < 0.1f) ? 1 : 0;  ne.x = 1 - e.x;
        e.y = (n1 < 0.1f) ? 1 : 0;  ne.y = 1 - e.y;
        e.z = (n2 < 0.1f) ? 1 : 0;  ne.z = 1 - e.z;
        e.w = (n3 < 0.1f) ? 1 : 0;  ne.w = 1 - e.w;
        reinterpret_cast<int4*>(edge)[i] = e;
        reinterpret_cast<int4*>(blurNe)[i] = ne;
    }
}

extern "C" void kernel_launch(void* const* d_in, const int* in_sizes, int n_in,
                              void* d_out, int out_size, void* d_ws, size_t ws_size,
                              hipStream_t stream) {
    const float* x = (const float*)d_in[0];
    int* out = (int*)d_out;
    const long long N = (long long)in_sizes[0];        // 33554432
    const int nimg = (int)(N / IMG_PIX);               // 128
    float* blur = (float*)(out + N);                   // scratch in 2nd output half
    int* mm = (int*)d_ws;                              // 2 ints per image

    // f32 Gaussian weights, mimicking the jnp float32 ops
    Weights wt;
    {
        float tmp[13];
        float s = 0.0f;
        for (int i = 0; i < 7; ++i) {
            float t = (float)i - 3.0f;
            float u = t / 10.0f;
            tmp[i] = expf(-0.5f * (u * u));
            s += tmp[i];
        }
        for (int i = 0; i < 7; ++i) wt.kx[i] = tmp[i] / s;
        s = 0.0f;
        for (int i = 0; i < 13; ++i) {
            float t = (float)i - 6.0f;
            float u = t / 10.0f;
            tmp[i] = expf(-0.5f * (u * u));
            s += tmp[i];
        }
        for (int i = 0; i < 13; ++i) wt.ky[i] = tmp[i] / s;
    }

    init_minmax_kernel<<<1, 256, 0, stream>>>(mm, nimg);
    blur_kernel<<<dim3(IMW / TW, IMH / TH, nimg), 256, 0, stream>>>(x, blur, mm, wt);
    mask_kernel<<<2048, 256, 0, stream>>>(mm, out, (int*)blur, N / 4);
}

// Round 5
// 252.113 us; speedup vs baseline: 1.8421x; 1.0726x over previous
//
#include <hip/hip_runtime.h>
#include <cmath>

// Problem geometry (fixed by the reference): 128 images of 512x512 f32.
static constexpr int IMH = 512;
static constexpr int IMW = 512;
static constexpr int IMG_PIX = IMH * IMW;

// Tile config
static constexpr int TH = 64;            // output tile height
static constexpr int TW = 64;            // output tile width
static constexpr int INR = 78;           // s_in rows  [Y0-7 .. Y0+70]
static constexpr int INC = 76;           // s_in cols  [X0-4 .. X0+71]
static constexpr int INC4 = 19;          // float4 per s_in row
static constexpr int GR = 76;            // grad rows  [Y0-6 .. Y0+69] (reflected)
static constexpr int GC = 70;            // grad cols  [X0-3 .. X0+66] (reflected)
static constexpr int GCP = 73;           // s_grad stride (odd-ish: 9r+c -> 2-way banks)
static constexpr int TWP = 65;           // s_bx stride (r+c -> 2-way banks)

struct Weights {
    float kx[7];
    float ky[13];
};

__global__ void init_minmax_kernel(int* __restrict__ mm, int nimg) {
    int i = blockIdx.x * blockDim.x + threadIdx.x;
    if (i < nimg) {
        mm[2 * i]     = 0x7f7fffff;  // +FLT_MAX bits (min accumulator)
        mm[2 * i + 1] = 0;           // 0.0f bits (max accumulator; blur > 0)
    }
}

// Fused: input tile -> Sobel-magnitude grad (reflection hoisted) -> 1x7 blur
// (register window) -> 13x1 blur (register window) -> blur store + minmax.
__global__ __launch_bounds__(256) void blur_kernel(
        const float* __restrict__ in, float* __restrict__ blur,
        int* __restrict__ mm, Weights wt) {
    __shared__ float s_grad[GR * GCP];            // 22192 B
    __shared__ float s_a[INR * INC];              // 23712 B (s_in, then s_bx)
    __shared__ float s_red[16];
    float* s_in = s_a;                            // [INR][INC]
    float* s_bx = s_a;                            // [GR][TWP] (19760 B, fits)

    const int img = blockIdx.z;
    const int X0 = blockIdx.x * TW;
    const int Y0 = blockIdx.y * TH;
    const int tid = threadIdx.x;
    const int by0 = Y0 - 7;                       // virtual tile origin
    const int bx0 = X0 - 4;
    const float* __restrict__ ip = in + (size_t)img * IMG_PIX;

    // wave-uniform: interior blocks need no clamping/reflection anywhere
    const bool interior = (X0 > 0) && (X0 < 448) && (Y0 > 0) && (Y0 < 448);

    // ---- stage 0: coalesced float4 load of input tile ----
    if (interior) {
        for (int idx = tid; idx < INR * INC4; idx += 256) {
            int r = idx / INC4;
            int q = idx - r * INC4;
            float4 v = *reinterpret_cast<const float4*>(
                ip + (size_t)(by0 + r) * IMW + bx0 + q * 4);
            *reinterpret_cast<float4*>(&s_in[r * INC + q * 4]) = v;
        }
    } else {
        for (int idx = tid; idx < INR * INC4; idx += 256) {
            int r = idx / INC4;
            int q = idx - r * INC4;
            int gy = by0 + r;
            gy = gy < 0 ? 0 : (gy > IMH - 1 ? IMH - 1 : gy);
            int gx = bx0 + q * 4;
            float4 v;
            if (gx >= 0 && gx <= IMW - 4) {
                v = *reinterpret_cast<const float4*>(ip + (size_t)gy * IMW + gx);
            } else {
                int g0 = min(max(gx, 0), IMW - 1);
                int g1 = min(max(gx + 1, 0), IMW - 1);
                int g2 = min(max(gx + 2, 0), IMW - 1);
                int g3 = min(max(gx + 3, 0), IMW - 1);
                const float* rp = ip + (size_t)gy * IMW;
                v = make_float4(rp[g0], rp[g1], rp[g2], rp[g3]);
            }
            *reinterpret_cast<float4*>(&s_in[r * INC + q * 4]) = v;
        }
    }
    __syncthreads();

    // ---- stage 1: Sobel-magnitude grad ----
    if (interior) {
        // no reflection, no guards: gy = Y0-6+lr in [58,453], gx in [61,450]
        int r = tid >> 2;
        int ch = tid & 3;
        int cbeg = ch * 18;
        int cnt = (ch == 3) ? 16 : 18;
        #pragma unroll
        for (int pass = 0; pass < 2; ++pass) {
            int lr = r + pass * 64;
            if (lr < GR) {
                int abase = (lr + 1) * INC + 1 + cbeg;
                int gbase = lr * GCP + cbeg;
                for (int j = 0; j < cnt; ++j) {
                    int a = abase + j;
                    float up = s_in[a - INC];
                    float dn = s_in[a + INC];
                    float lf = s_in[a - 1];
                    float rt = s_in[a + 1];
                    float gv = dn - up;
                    float gh = rt - lf;
                    float sa = gv * gv;
                    float sb = gh * gh;
                    asm volatile("" : "+v"(sa), "+v"(sb));  // block fma contraction
                    float s = sa + sb;
                    asm volatile("" : "+v"(s));
                    s = s + 1e-6f;
                    s_grad[gbase + j] = sqrtf(s);
                }
            }
        }
    } else {
        for (int idx = tid; idx < GR * GC; idx += 256) {
            int lr = idx / GC;
            int lc = idx - lr * GC;
            int gy = Y0 - 6 + lr;
            gy = gy < 0 ? -gy : (gy > IMH - 1 ? 2 * (IMH - 1) - gy : gy);
            int gx = X0 - 3 + lc;
            gx = gx < 0 ? -gx : (gx > IMW - 1 ? 2 * (IMW - 1) - gx : gx);
            int a = (gy - by0) * INC + (gx - bx0);
            float up = (gy > 0)       ? s_in[a - INC] : 0.0f;
            float dn = (gy < IMH - 1) ? s_in[a + INC] : 0.0f;
            float lf = (gx > 0)       ? s_in[a - 1]   : 0.0f;
            float rt = (gx < IMW - 1) ? s_in[a + 1]   : 0.0f;
            float gv = dn - up;
            float gh = rt - lf;
            float sa = gv * gv;
            float sb = gh * gh;
            asm volatile("" : "+v"(sa), "+v"(sb));
            float s = sa + sb;
            asm volatile("" : "+v"(s));
            s = s + 1e-6f;
            s_grad[lr * GCP + lc] = sqrtf(s);
        }
    }
    __syncthreads();

    // ---- stage 2: horizontal 7-tap blur, 16-wide register window ----
    for (int t = tid; t < GR * 4; t += 256) {
        int r = t >> 2;
        int c0 = (t & 3) * 16;
        float g[22];
        #pragma unroll
        for (int k = 0; k < 22; ++k) g[k] = s_grad[r * GCP + c0 + k];
        #pragma unroll
        for (int k = 0; k < 16; ++k) {
            float acc = 0.0f;
            #pragma unroll
            for (int i = 0; i < 7; ++i) {
                float p = wt.kx[i] * g[k + i];
                asm volatile("" : "+v"(p));  // plain mul + add
                acc += p;
            }
            s_bx[r * TWP + c0 + k] = acc;
        }
    }
    __syncthreads();

    // ---- stage 3: vertical 13-tap blur, 16-tall register window + minmax ----
    float tmn = 3.402823466e38f;
    float tmx = 0.0f;
    {
        int c = tid & 63;
        int r0 = (tid >> 6) * 16;       // 0,16,32,48
        float w[28];
        #pragma unroll
        for (int t = 0; t < 28; ++t) w[t] = s_bx[(r0 + t) * TWP + c];
        float* __restrict__ bp = blur + (size_t)img * IMG_PIX;
        #pragma unroll
        for (int k = 0; k < 16; ++k) {
            float acc = 0.0f;
            #pragma unroll
            for (int j = 0; j < 13; ++j) {
                float p = wt.ky[j] * w[k + j];
                asm volatile("" : "+v"(p));
                acc += p;
            }
            bp[(size_t)(Y0 + r0 + k) * IMW + X0 + c] = acc;
            tmn = fminf(tmn, acc);
            tmx = fmaxf(tmx, acc);
        }
    }

    // wave (64-lane) butterfly reduce, then across the 4 waves, then atomics
    #pragma unroll
    for (int off = 32; off > 0; off >>= 1) {
        tmn = fminf(tmn, __shfl_xor(tmn, off));
        tmx = fmaxf(tmx, __shfl_xor(tmx, off));
    }
    int wid = tid >> 6;
    if ((tid & 63) == 0) {
        s_red[wid] = tmn;
        s_red[8 + wid] = tmx;
    }
    __syncthreads();
    if (tid == 0) {
        float mn = s_red[0], mx = s_red[8];
        #pragma unroll
        for (int w2 = 1; w2 < 4; ++w2) {
            mn = fminf(mn, s_red[w2]);
            mx = fmaxf(mx, s_red[8 + w2]);
        }
        // blur values are strictly positive -> float order == int order
        atomicMin(&mm[2 * img], __float_as_int(mn));
        atomicMax(&mm[2 * img + 1], __float_as_int(mx));
    }
}

// Normalize + emit both masks as INT32 0/1 (bool output dtype -> int32).
// blurNe holds blur f32 bit patterns on entry (second half of d_out used as
// scratch); each thread overwrites exactly the elements it read.
__global__ __launch_bounds__(256) void mask_kernel(
        const int* __restrict__ mm, int* __restrict__ edge,
        int* __restrict__ blurNe, long long n4) {
    const long long stride = (long long)gridDim.x * blockDim.x;
    for (long long i = (long long)blockIdx.x * blockDim.x + threadIdx.x;
         i < n4; i += stride) {
        int img = (int)(i >> 16);  // 262144/4 = 65536 vec4 per image
        float mn = __int_as_float(mm[2 * img]);
        float mx = __int_as_float(mm[2 * img + 1]);
        float d = mx - mn;
        int4 vi = reinterpret_cast<const int4*>(blurNe)[i];
        float4 v = make_float4(__int_as_float(vi.x), __int_as_float(vi.y),
                               __int_as_float(vi.z), __int_as_float(vi.w));
        // true division to match reference normalization exactly
        float n0 = (v.x - mn) / d;
        float n1 = (v.y - mn) / d;
        float n2 = (v.z - mn) / d;
        float n3 = (v.w - mn) / d;
        int4 e, ne;
        e.x = (n0 < 0.1f) ? 1 : 0;  ne.x = 1 - e.x;
        e.y = (n1 < 0.1f) ? 1 : 0;  ne.y = 1 - e.y;
        e.z = (n2 < 0.1f) ? 1 : 0;  ne.z = 1 - e.z;
        e.w = (n3 < 0.1f) ? 1 : 0;  ne.w = 1 - e.w;
        reinterpret_cast<int4*>(edge)[i] = e;
        reinterpret_cast<int4*>(blurNe)[i] = ne;
    }
}

extern "C" void kernel_launch(void* const* d_in, const int* in_sizes, int n_in,
                              void* d_out, int out_size, void* d_ws, size_t ws_size,
                              hipStream_t stream) {
    const float* x = (const float*)d_in[0];
    int* out = (int*)d_out;
    const long long N = (long long)in_sizes[0];        // 33554432
    const int nimg = (int)(N / IMG_PIX);               // 128
    float* blur = (float*)(out + N);                   // scratch in 2nd output half
    int* mm = (int*)d_ws;                              // 2 ints per image

    // f32 Gaussian weights, mimicking the jnp float32 ops
    Weights wt;
    {
        float tmp[13];
        float s = 0.0f;
        for (int i = 0; i < 7; ++i) {
            float t = (float)i - 3.0f;
            float u = t / 10.0f;
            tmp[i] = expf(-0.5f * (u * u));
            s += tmp[i];
        }
        for (int i = 0; i < 7; ++i) wt.kx[i] = tmp[i] / s;
        s = 0.0f;
        for (int i = 0; i < 13; ++i) {
            float t = (float)i - 6.0f;
            float u = t / 10.0f;
            tmp[i] = expf(-0.5f * (u * u));
            s += tmp[i];
        }
        for (int i = 0; i < 13; ++i) wt.ky[i] = tmp[i] / s;
    }

    init_minmax_kernel<<<1, 256, 0, stream>>>(mm, nimg);
    blur_kernel<<<dim3(IMW / TW, IMH / TH, nimg), 256, 0, stream>>>(x, blur, mm, wt);
    mask_kernel<<<2048, 256, 0, stream>>>(mm, out, (int*)blur, N / 4);
}

// Round 6
// 235.060 us; speedup vs baseline: 1.9757x; 1.0725x over previous
//
#include <hip/hip_runtime.h>
#include <cmath>

// Problem geometry (fixed by the reference): 128 images of 512x512 f32.
static constexpr int IMH = 512;
static constexpr int IMW = 512;
static constexpr int IMG_PIX = IMH * IMW;

struct Weights {
    float kx[7];
    float ky[13];
};

__global__ void init_minmax_kernel(int* __restrict__ mm, int nimg) {
    int i = blockIdx.x * blockDim.x + threadIdx.x;
    if (i < nimg) {
        mm[2 * i]     = 0x7f7fffff;  // +FLT_MAX bits (min accumulator)
        mm[2 * i + 1] = 0;           // 0.0f bits (max accumulator; blur > 0)
    }
}

// Column-sweep fused kernel: zero LDS, zero barriers.
// Wave = 64 lanes <-> 64 columns (56 outputs + 3+1 / 3+1 halo). 4 waves per
// block sweep 4 independent 128-row chunks. Per row: grad via register
// history + 2 shuffles, blurX via 6 shuffles (reflect folded into per-lane
// source-lane table), blurY via 13-register ring with static indexing.
__global__ __launch_bounds__(256) void blur_kernel(
        const float* __restrict__ in, float* __restrict__ blur,
        int* __restrict__ mm, Weights wt) {
    const int band = blockIdx.x;              // 0..9
    const int img  = blockIdx.y;              // 0..127
    const int k    = threadIdx.x >> 6;        // row chunk 0..3
    const int lane = threadIdx.x & 63;
    const int cb   = band * 56 - 4;           // wave covers cols cb..cb+63
    const int c    = cb + lane;
    const bool load_ok = (c >= 0) && (c <= IMW - 1);
    const bool cvalid  = (lane >= 4) && (lane <= 59) && (c <= IMW - 1);
    const bool has_l   = (c >= 1);
    const bool has_r   = (c <= IMW - 2);

    const float* __restrict__ ip = in + (size_t)img * IMG_PIX;
    float* __restrict__ bp = blur + (size_t)img * IMG_PIX;

    // Per-lane blurX tap source lanes, reflection folded in (tap i, offset i-3).
    int srcl[7];
    #pragma unroll
    for (int i = 0; i < 7; ++i) {
        int tc = c + i - 3;
        tc = tc < 0 ? -tc : (tc > IMW - 1 ? 2 * (IMW - 1) - tc : tc);
        srcl[i] = tc - cb;  // in [0,63] for every consumed lane
    }

    const int gr0    = (k == 0) ? 0 : 128 * k - 6;       // first bx row
    const int gr_end = (k == 3) ? IMH - 1 : 128 * k + 133;
    const int or_hi  = (k == 3) ? 505 : 128 * k + 127;

    // x register pipeline: rows gr-1, gr, gr+1 (+1 prefetch)
    float x_prev = (gr0 > 0 && load_ok) ? ip[(gr0 - 1) * IMW + c] : 0.0f;
    float x_cur  = load_ok ? ip[gr0 * IMW + c] : 0.0f;
    float x_next = load_ok ? ip[(gr0 + 1) * IMW + c] : 0.0f;

    float w[13];                                          // bx ring, static idx
    float tmn = 3.402823466e38f;
    float tmx = 0.0f;

    for (int giter = 0; giter < 11; ++giter) {
        #pragma unroll
        for (int s = 0; s < 13; ++s) {
            int gr = gr0 + giter * 13 + s;
            if (gr <= gr_end) {
                // prefetch row gr+2
                float x_pref = 0.0f;
                if (gr + 2 <= IMH - 1 && load_ok) x_pref = ip[(gr + 2) * IMW + c];

                // ---- grad row gr (zero-pad at true image edges) ----
                float xl = __shfl(x_cur, lane - 1);
                float xr = __shfl(x_cur, lane + 1);
                float lf = has_l ? xl : 0.0f;
                float rt = has_r ? xr : 0.0f;
                float up = x_prev;          // zeroed at row 0 by pipeline init
                float dn = (gr == IMH - 1) ? 0.0f : x_next;
                float gv = dn - up;
                float gh = rt - lf;
                float sa = gv * gv;
                float sb = gh * gh;
                asm volatile("" : "+v"(sa), "+v"(sb));  // block fma contraction
                float sg = sa + sb;
                asm volatile("" : "+v"(sg));
                sg = sg + 1e-6f;
                float g = sqrtf(sg);

                // ---- blurX row gr: 7 taps via shuffles (reflect in srcl) ----
                float t0 = __shfl(g, srcl[0]);
                float t1 = __shfl(g, srcl[1]);
                float t2 = __shfl(g, srcl[2]);
                float t4 = __shfl(g, srcl[4]);
                float t5 = __shfl(g, srcl[5]);
                float t6 = __shfl(g, srcl[6]);
                float tap[7] = {t0, t1, t2, g, t4, t5, t6};
                float acc = 0.0f;
                #pragma unroll
                for (int i = 0; i < 7; ++i) {
                    float p = wt.kx[i] * tap[i];
                    asm volatile("" : "+v"(p));  // plain mul + add
                    acc += p;
                }
                w[s] = acc;   // ring slot = (gr - gr0) % 13 == s

                // ---- top reflected outputs (k==0 only, rows 0..5) ----
                if (s >= 6 && k == 0 && giter == 0) {
                    int orow = s - 6;
                    float acc2 = 0.0f;
                    #pragma unroll
                    for (int j = 0; j < 13; ++j) {
                        int t = orow + j - 6;
                        t = t < 0 ? -t : t;          // static per (s,j)
                        float p = wt.ky[j] * w[t];   // rows 0..11 at slots 0..11
                        asm volatile("" : "+v"(p));
                        acc2 += p;
                    }
                    if (cvalid) {
                        bp[(size_t)orow * IMW + c] = acc2;
                        tmn = fminf(tmn, acc2);
                        tmx = fmaxf(tmx, acc2);
                    }
                }

                // ---- regular output row gr-6 (window rows gr-12..gr) ----
                if (gr >= gr0 + 12) {
                    int orow = gr - 6;
                    if (orow <= or_hi) {
                        float acc2 = 0.0f;
                        #pragma unroll
                        for (int j = 0; j < 13; ++j) {
                            float p = wt.ky[j] * w[(s + 1 + j) % 13];
                            asm volatile("" : "+v"(p));
                            acc2 += p;
                        }
                        if (cvalid) {
                            bp[(size_t)orow * IMW + c] = acc2;
                            tmn = fminf(tmn, acc2);
                            tmx = fmaxf(tmx, acc2);
                        }
                    }
                }

                // rotate pipeline
                x_prev = x_cur;
                x_cur  = x_next;
                x_next = x_pref;
            }
        }
    }

    // ---- bottom reflected outputs (k==3 only, rows 506..511) ----
    // After final iter, row t (500..511) sits at slot (t - 378) % 13.
    if (k == 3) {
        #pragma unroll
        for (int oo = 0; oo < 6; ++oo) {
            int orow = 506 + oo;
            float acc2 = 0.0f;
            #pragma unroll
            for (int j = 0; j < 13; ++j) {
                int t = orow + j - 6;
                t = t > IMH - 1 ? 2 * (IMH - 1) - t : t;  // static
                float p = wt.ky[j] * w[(t - 378) % 13];
                asm volatile("" : "+v"(p));
                acc2 += p;
            }
            if (cvalid) {
                bp[(size_t)orow * IMW + c] = acc2;
                tmn = fminf(tmn, acc2);
                tmx = fmaxf(tmx, acc2);
            }
        }
    }

    // ---- per-wave reduce + per-image atomics ----
    #pragma unroll
    for (int off = 32; off > 0; off >>= 1) {
        tmn = fminf(tmn, __shfl_xor(tmn, off));
        tmx = fmaxf(tmx, __shfl_xor(tmx, off));
    }
    if (lane == 0) {
        // blur values strictly positive -> float order == int order
        atomicMin(&mm[2 * img], __float_as_int(tmn));
        atomicMax(&mm[2 * img + 1], __float_as_int(tmx));
    }
}

// Normalize + emit both masks as INT32 0/1 (bool output dtype -> int32).
// blurNe holds blur f32 bit patterns on entry (second half of d_out used as
// scratch); each thread overwrites exactly the elements it read.
__global__ __launch_bounds__(256) void mask_kernel(
        const int* __restrict__ mm, int* __restrict__ edge,
        int* __restrict__ blurNe, long long n4) {
    const long long stride = (long long)gridDim.x * blockDim.x;
    for (long long i = (long long)blockIdx.x * blockDim.x + threadIdx.x;
         i < n4; i += stride) {
        int img = (int)(i >> 16);  // 262144/4 = 65536 vec4 per image
        float mn = __int_as_float(mm[2 * img]);
        float mx = __int_as_float(mm[2 * img + 1]);
        float d = mx - mn;
        int4 vi = reinterpret_cast<const int4*>(blurNe)[i];
        float4 v = make_float4(__int_as_float(vi.x), __int_as_float(vi.y),
                               __int_as_float(vi.z), __int_as_float(vi.w));
        // true division to match reference normalization exactly
        float n0 = (v.x - mn) / d;
        float n1 = (v.y - mn) / d;
        float n2 = (v.z - mn) / d;
        float n3 = (v.w - mn) / d;
        int4 e, ne;
        e.x = (n0 < 0.1f) ? 1 : 0;  ne.x = 1 - e.x;
        e.y = (n1 < 0.1f) ? 1 : 0;  ne.y = 1 - e.y;
        e.z = (n2 < 0.1f) ? 1 : 0;  ne.z = 1 - e.z;
        e.w = (n3 < 0.1f) ? 1 : 0;  ne.w = 1 - e.w;
        reinterpret_cast<int4*>(edge)[i] = e;
        reinterpret_cast<int4*>(blurNe)[i] = ne;
    }
}

extern "C" void kernel_launch(void* const* d_in, const int* in_sizes, int n_in,
                              void* d_out, int out_size, void* d_ws, size_t ws_size,
                              hipStream_t stream) {
    const float* x = (const float*)d_in[0];
    int* out = (int*)d_out;
    const long long N = (long long)in_sizes[0];        // 33554432
    const int nimg = (int)(N / IMG_PIX);               // 128
    float* blur = (float*)(out + N);                   // scratch in 2nd output half
    int* mm = (int*)d_ws;                              // 2 ints per image

    // f32 Gaussian weights, mimicking the jnp float32 ops
    Weights wt;
    {
        float tmp[13];
        float s = 0.0f;
        for (int i = 0; i < 7; ++i) {
            float t = (float)i - 3.0f;
            float u = t / 10.0f;
            tmp[i] = expf(-0.5f * (u * u));
            s += tmp[i];
        }
        for (int i = 0; i < 7; ++i) wt.kx[i] = tmp[i] / s;
        s = 0.0f;
        for (int i = 0; i < 13; ++i) {
            float t = (float)i - 6.0f;
            float u = t / 10.0f;
            tmp[i] = expf(-0.5f * (u * u));
            s += tmp[i];
        }
        for (int i = 0; i < 13; ++i) wt.ky[i] = tmp[i] / s;
    }

    init_minmax_kernel<<<1, 256, 0, stream>>>(mm, nimg);
    blur_kernel<<<dim3(10, nimg), 256, 0, stream>>>(x, blur, mm, wt);
    mask_kernel<<<2048, 256, 0, stream>>>(mm, out, (int*)blur, N / 4);
}

// Round 7
// 227.408 us; speedup vs baseline: 2.0422x; 1.0336x over previous
//
#include <hip/hip_runtime.h>
#include <cmath>

// Problem geometry (fixed by the reference): 128 images of 512x512 f32.
static constexpr int IMH = 512;
static constexpr int IMW = 512;
static constexpr int IMG_PIX = IMH * IMW;

struct Weights {
    float kx[7];
    float ky[13];
};

__global__ void init_minmax_kernel(int* __restrict__ mm, int nimg) {
    int i = blockIdx.x * blockDim.x + threadIdx.x;
    if (i < nimg) {
        mm[2 * i]     = 0x7f7fffff;  // +FLT_MAX bits (min accumulator)
        mm[2 * i + 1] = 0;           // 0.0f bits (max accumulator; blur > 0)
    }
}

// Column-sweep fused kernel: zero LDS, zero barriers, zero bank conflicts.
// Wave = 64 lanes <-> 64 columns (56 outputs + halo). 4 waves per block sweep
// 4 independent ~134/140-row chunks. Per row: grad via register history + 2
// bpermutes (precomputed addrs), blurX via 6 bpermutes (reflect folded into
// the address table), blurY via a 13-register ring with static indexing.
// All asm contraction-barriers are NON-volatile: they block FMA fusion but
// allow full instruction scheduling. Main loop is guard-free by construction.
__global__ __launch_bounds__(256) void blur_kernel(
        const float* __restrict__ in, float* __restrict__ blur,
        int* __restrict__ mm, Weights wt) {
    const int band = blockIdx.x;              // 0..9
    const int img  = blockIdx.y;              // 0..127
    const int k    = threadIdx.x >> 6;        // row chunk 0..3
    const int lane = threadIdx.x & 63;
    const int cb   = band * 56 - 4;           // wave covers cols cb..cb+63
    const int c    = cb + lane;
    const int c_ld = min(max(c, 0), IMW - 1); // clamped load col (dead lanes)
    const bool cvalid = (lane >= 4) && (lane <= 59) && (c <= IMW - 1);
    const bool has_l  = (c >= 1);
    const bool has_r  = (c <= IMW - 2);

    const float* __restrict__ ip = in + (size_t)img * IMG_PIX;
    float* __restrict__ bp = blur + (size_t)img * IMG_PIX;

    // Precomputed ds_bpermute byte addresses.
    const int a_lm1 = ((lane + 63) & 63) << 2;
    const int a_lp1 = ((lane + 1) & 63) << 2;
    int sb0, sb1, sb2, sb4, sb5, sb6;
    {
        int t;
        t = c - 3; t = t < 0 ? -t : (t > IMW - 1 ? 2 * (IMW - 1) - t : t); sb0 = ((t - cb) & 63) << 2;
        t = c - 2; t = t < 0 ? -t : (t > IMW - 1 ? 2 * (IMW - 1) - t : t); sb1 = ((t - cb) & 63) << 2;
        t = c - 1; t = t < 0 ? -t : (t > IMW - 1 ? 2 * (IMW - 1) - t : t); sb2 = ((t - cb) & 63) << 2;
        t = c + 1; t = t < 0 ? -t : (t > IMW - 1 ? 2 * (IMW - 1) - t : t); sb4 = ((t - cb) & 63) << 2;
        t = c + 2; t = t < 0 ? -t : (t > IMW - 1 ? 2 * (IMW - 1) - t : t); sb5 = ((t - cb) & 63) << 2;
        t = c + 3; t = t < 0 ? -t : (t > IMW - 1 ? 2 * (IMW - 1) - t : t); sb6 = ((t - cb) & 63) << 2;
    }

    const int gr0    = (k == 0) ? 0 : 128 * k - 6;       // first bx row
    const int gr_end = (k == 3) ? IMH - 1 : 128 * k + 133;
    const int tail_n = gr_end - gr0 - 129;               // 4 or 10

    // x register pipeline: rows gr-1, gr, gr+1 (+1 prefetch), moving pointers
    const float* xp = ip + (size_t)gr0 * IMW + c_ld;
    float x_prev = (k == 0) ? 0.0f : xp[-IMW];
    float x_cur  = xp[0];
    float x_next = xp[IMW];
    const float* xp_pref = xp + 2 * (size_t)IMW;
    float* op = bp + (size_t)(gr0 + 6) * IMW + c;        // first regular orow

    float w[13];                                          // bx ring, static idx
    float tmn = 3.402823466e38f;
    float tmx = 0.0f;

#define GM_ROW(S, DO_OUT, DN, PREF)                                            \
    {                                                                          \
        float x_pref = (PREF);                                                 \
        int xi_ = __float_as_int(x_cur);                                       \
        float xl_ = __int_as_float(__builtin_amdgcn_ds_bpermute(a_lm1, xi_));  \
        float xr_ = __int_as_float(__builtin_amdgcn_ds_bpermute(a_lp1, xi_));  \
        float lf_ = has_l ? xl_ : 0.0f;                                        \
        float rt_ = has_r ? xr_ : 0.0f;                                        \
        float gv_ = (DN) - x_prev;                                             \
        float gh_ = rt_ - lf_;                                                 \
        float sa_ = gv_ * gv_;                                                 \
        float sb_ = gh_ * gh_;                                                 \
        asm("" : "+v"(sa_), "+v"(sb_));  /* block fma contraction */           \
        float sg_ = sa_ + sb_;                                                 \
        asm("" : "+v"(sg_));                                                   \
        sg_ = sg_ + 1e-6f;                                                     \
        float g_ = sqrtf(sg_);                                                 \
        int gi_ = __float_as_int(g_);                                          \
        float b0_ = __int_as_float(__builtin_amdgcn_ds_bpermute(sb0, gi_));    \
        float b1_ = __int_as_float(__builtin_amdgcn_ds_bpermute(sb1, gi_));    \
        float b2_ = __int_as_float(__builtin_amdgcn_ds_bpermute(sb2, gi_));    \
        float b4_ = __int_as_float(__builtin_amdgcn_ds_bpermute(sb4, gi_));    \
        float b5_ = __int_as_float(__builtin_amdgcn_ds_bpermute(sb5, gi_));    \
        float b6_ = __int_as_float(__builtin_amdgcn_ds_bpermute(sb6, gi_));    \
        float ax_ = 0.0f, p_;                                                  \
        p_ = wt.kx[0] * b0_; asm("" : "+v"(p_)); ax_ += p_;                    \
        p_ = wt.kx[1] * b1_; asm("" : "+v"(p_)); ax_ += p_;                    \
        p_ = wt.kx[2] * b2_; asm("" : "+v"(p_)); ax_ += p_;                    \
        p_ = wt.kx[3] * g_;  asm("" : "+v"(p_)); ax_ += p_;                    \
        p_ = wt.kx[4] * b4_; asm("" : "+v"(p_)); ax_ += p_;                    \
        p_ = wt.kx[5] * b5_; asm("" : "+v"(p_)); ax_ += p_;                    \
        p_ = wt.kx[6] * b6_; asm("" : "+v"(p_)); ax_ += p_;                    \
        w[(S) % 13] = ax_;                                                     \
        if (DO_OUT) {                                                          \
            float ay_ = 0.0f;                                                  \
            p_ = wt.ky[0]  * w[((S) + 1)  % 13]; asm("" : "+v"(p_)); ay_ += p_;\
            p_ = wt.ky[1]  * w[((S) + 2)  % 13]; asm("" : "+v"(p_)); ay_ += p_;\
            p_ = wt.ky[2]  * w[((S) + 3)  % 13]; asm("" : "+v"(p_)); ay_ += p_;\
            p_ = wt.ky[3]  * w[((S) + 4)  % 13]; asm("" : "+v"(p_)); ay_ += p_;\
            p_ = wt.ky[4]  * w[((S) + 5)  % 13]; asm("" : "+v"(p_)); ay_ += p_;\
            p_ = wt.ky[5]  * w[((S) + 6)  % 13]; asm("" : "+v"(p_)); ay_ += p_;\
            p_ = wt.ky[6]  * w[((S) + 7)  % 13]; asm("" : "+v"(p_)); ay_ += p_;\
            p_ = wt.ky[7]  * w[((S) + 8)  % 13]; asm("" : "+v"(p_)); ay_ += p_;\
            p_ = wt.ky[8]  * w[((S) + 9)  % 13]; asm("" : "+v"(p_)); ay_ += p_;\
            p_ = wt.ky[9]  * w[((S) + 10) % 13]; asm("" : "+v"(p_)); ay_ += p_;\
            p_ = wt.ky[10] * w[((S) + 11) % 13]; asm("" : "+v"(p_)); ay_ += p_;\
            p_ = wt.ky[11] * w[((S) + 12) % 13]; asm("" : "+v"(p_)); ay_ += p_;\
            p_ = wt.ky[12] * w[((S) + 13) % 13]; asm("" : "+v"(p_)); ay_ += p_;\
            if (cvalid) {                                                      \
                *op = ay_;                                                     \
                tmn = fminf(tmn, ay_);                                         \
                tmx = fmaxf(tmx, ay_);                                         \
            }                                                                  \
            op += IMW;                                                         \
        }                                                                      \
        x_prev = x_cur; x_cur = x_next; x_next = x_pref;                       \
        xp_pref += IMW;                                                        \
    }

    // ---- peel: ring fill, rows gr0..gr0+12 (one output at s=12) ----
    GM_ROW(0,  false, x_next, xp_pref[0])
    GM_ROW(1,  false, x_next, xp_pref[0])
    GM_ROW(2,  false, x_next, xp_pref[0])
    GM_ROW(3,  false, x_next, xp_pref[0])
    GM_ROW(4,  false, x_next, xp_pref[0])
    GM_ROW(5,  false, x_next, xp_pref[0])
    GM_ROW(6,  false, x_next, xp_pref[0])
    GM_ROW(7,  false, x_next, xp_pref[0])
    GM_ROW(8,  false, x_next, xp_pref[0])
    GM_ROW(9,  false, x_next, xp_pref[0])
    GM_ROW(10, false, x_next, xp_pref[0])
    GM_ROW(11, false, x_next, xp_pref[0])
    GM_ROW(12, true,  x_next, xp_pref[0])

    // ---- top reflected outputs (k==0: rows 0..5 from ring rows 0..11) ----
    if (k == 0) {
        #pragma unroll
        for (int orow = 0; orow < 6; ++orow) {
            float ay = 0.0f;
            #pragma unroll
            for (int j = 0; j < 13; ++j) {
                int t = orow + j - 6;
                t = t < 0 ? -t : t;              // compile-time per (orow,j)
                float p2 = wt.ky[j] * w[t];      // slot == row for k==0
                asm("" : "+v"(p2));
                ay += p2;
            }
            if (cvalid) {
                bp[(size_t)orow * IMW + c] = ay;
                tmn = fminf(tmn, ay);
                tmx = fmaxf(tmx, ay);
            }
        }
    }

    // ---- main loop: rows gr0+13 .. gr0+129, fully guard-free ----
    for (int giter = 1; giter <= 9; ++giter) {
        GM_ROW(0,  true, x_next, xp_pref[0])
        GM_ROW(1,  true, x_next, xp_pref[0])
        GM_ROW(2,  true, x_next, xp_pref[0])
        GM_ROW(3,  true, x_next, xp_pref[0])
        GM_ROW(4,  true, x_next, xp_pref[0])
        GM_ROW(5,  true, x_next, xp_pref[0])
        GM_ROW(6,  true, x_next, xp_pref[0])
        GM_ROW(7,  true, x_next, xp_pref[0])
        GM_ROW(8,  true, x_next, xp_pref[0])
        GM_ROW(9,  true, x_next, xp_pref[0])
        GM_ROW(10, true, x_next, xp_pref[0])
        GM_ROW(11, true, x_next, xp_pref[0])
        GM_ROW(12, true, x_next, xp_pref[0])
    }

    // ---- tail: rows gr0+130 .. gr_end (4 or 10 rows), guarded ----
    // slot (130+S)%13 == S; row 511 (k==3, S==3) takes dn=0; prefetch guarded.
#define GM_TAILROW(S)                                                          \
    if ((S) < tail_n) {                                                        \
        GM_ROW(S, true,                                                        \
               ((gr0 + 130 + (S)) == IMH - 1) ? 0.0f : x_next,                 \
               ((gr0 + 132 + (S)) <= IMH - 1) ? xp_pref[0] : 0.0f)             \
    }
    GM_TAILROW(0)
    GM_TAILROW(1)
    GM_TAILROW(2)
    GM_TAILROW(3)
    GM_TAILROW(4)
    GM_TAILROW(5)
    GM_TAILROW(6)
    GM_TAILROW(7)
    GM_TAILROW(8)
    GM_TAILROW(9)
#undef GM_TAILROW
#undef GM_ROW

    // ---- bottom reflected outputs (k==3: rows 506..511) ----
    // Row t (500..511) sits at slot (t-378)%13 after the sweep.
    if (k == 3) {
        #pragma unroll
        for (int oo = 0; oo < 6; ++oo) {
            int orow = 506 + oo;
            float ay = 0.0f;
            #pragma unroll
            for (int j = 0; j < 13; ++j) {
                int t = orow + j - 6;
                t = t > IMH - 1 ? 2 * (IMH - 1) - t : t;  // compile-time
                float p2 = wt.ky[j] * w[(t - 378) % 13];
                asm("" : "+v"(p2));
                ay += p2;
            }
            if (cvalid) {
                bp[(size_t)orow * IMW + c] = ay;
                tmn = fminf(tmn, ay);
                tmx = fmaxf(tmx, ay);
            }
        }
    }

    // ---- per-wave reduce + per-image atomics ----
    #pragma unroll
    for (int off = 32; off > 0; off >>= 1) {
        tmn = fminf(tmn, __shfl_xor(tmn, off));
        tmx = fmaxf(tmx, __shfl_xor(tmx, off));
    }
    if (lane == 0) {
        // blur values strictly positive -> float order == int order
        atomicMin(&mm[2 * img], __float_as_int(tmn));
        atomicMax(&mm[2 * img + 1], __float_as_int(tmx));
    }
}

// Normalize + emit both masks as INT32 0/1 (bool output dtype -> int32).
// blurNe holds blur f32 bit patterns on entry (second half of d_out used as
// scratch); each thread overwrites exactly the elements it read.
__global__ __launch_bounds__(256) void mask_kernel(
        const int* __restrict__ mm, int* __restrict__ edge,
        int* __restrict__ blurNe, long long n4) {
    const long long stride = (long long)gridDim.x * blockDim.x;
    for (long long i = (long long)blockIdx.x * blockDim.x + threadIdx.x;
         i < n4; i += stride) {
        int img = (int)(i >> 16);  // 262144/4 = 65536 vec4 per image
        float mn = __int_as_float(mm[2 * img]);
        float mx = __int_as_float(mm[2 * img + 1]);
        float d = mx - mn;
        int4 vi = reinterpret_cast<const int4*>(blurNe)[i];
        float4 v = make_float4(__int_as_float(vi.x), __int_as_float(vi.y),
                               __int_as_float(vi.z), __int_as_float(vi.w));
        // true division to match reference normalization exactly
        float n0 = (v.x - mn) / d;
        float n1 = (v.y - mn) / d;
        float n2 = (v.z - mn) / d;
        float n3 = (v.w - mn) / d;
        int4 e, ne;
        e.x = (n0 < 0.1f) ? 1 : 0;  ne.x = 1 - e.x;
        e.y = (n1 < 0.1f) ? 1 : 0;  ne.y = 1 - e.y;
        e.z = (n2 < 0.1f) ? 1 : 0;  ne.z = 1 - e.z;
        e.w = (n3 < 0.1f) ? 1 : 0;  ne.w = 1 - e.w;
        reinterpret_cast<int4*>(edge)[i] = e;
        reinterpret_cast<int4*>(blurNe)[i] = ne;
    }
}

extern "C" void kernel_launch(void* const* d_in, const int* in_sizes, int n_in,
                              void* d_out, int out_size, void* d_ws, size_t ws_size,
                              hipStream_t stream) {
    const float* x = (const float*)d_in[0];
    int* out = (int*)d_out;
    const long long N = (long long)in_sizes[0];        // 33554432
    const int nimg = (int)(N / IMG_PIX);               // 128
    float* blur = (float*)(out + N);                   // scratch in 2nd output half
    int* mm = (int*)d_ws;                              // 2 ints per image

    // f32 Gaussian weights, mimicking the jnp float32 ops
    Weights wt;
    {
        float tmp[13];
        float s = 0.0f;
        for (int i = 0; i < 7; ++i) {
            float t = (float)i - 3.0f;
            float u = t / 10.0f;
            tmp[i] = expf(-0.5f * (u * u));
            s += tmp[i];
        }
        for (int i = 0; i < 7; ++i) wt.kx[i] = tmp[i] / s;
        s = 0.0f;
        for (int i = 0; i < 13; ++i) {
            float t = (float)i - 6.0f;
            float u = t / 10.0f;
            tmp[i] = expf(-0.5f * (u * u));
            s += tmp[i];
        }
        for (int i = 0; i < 13; ++i) wt.ky[i] = tmp[i] / s;
    }

    init_minmax_kernel<<<1, 256, 0, stream>>>(mm, nimg);
    blur_kernel<<<dim3(10, nimg), 256, 0, stream>>>(x, blur, mm, wt);
    mask_kernel<<<2048, 256, 0, stream>>>(mm, out, (int*)blur, N / 4);
}